// Round 13
// baseline (431.718 us; speedup 1.0000x reference)
//
#include <hip/hip_runtime.h>
#include <hip/hip_bf16.h>
#include <stdint.h>

typedef float  f32x4  __attribute__((ext_vector_type(4)));
typedef short  s16x8  __attribute__((ext_vector_type(8)));
typedef unsigned short u16;

#define BK 32

__device__ inline u16 f32_to_bf16_rn(float f) {
  uint32_t u = __builtin_bit_cast(uint32_t, f);
  u += 0x7FFFu + ((u >> 16) & 1u);
  return (u16)(u >> 16);
}
__device__ inline float bf16u_to_f32(u16 h) {
  uint32_t u = ((uint32_t)h) << 16;
  return __builtin_bit_cast(float, u);
}
__device__ inline void split2(float x, u16& hi, u16& lo) {
  u16 h = f32_to_bf16_rn(x);
  lo = f32_to_bf16_rn(x - bf16u_to_f32(h));
  hi = h;
}

__device__ inline void stage16(const u16* g, const u16* l) {
  __builtin_amdgcn_global_load_lds((const __attribute__((address_space(1))) uint32_t*)g,
                                   (__attribute__((address_space(3))) uint32_t*)(u16*)l,
                                   16, 0, 0);
}

// XCD-aware block swizzle (m204 bijective; needs gridDim.x*gridDim.y % 8 == 0)
__device__ inline void xcd_swz(int& bx, int& by) {
  int nx = gridDim.x, nwg = nx * gridDim.y;
  if ((nwg & 7) == 0) {
    int wg = blockIdx.x + nx * blockIdx.y;
    int s = (wg & 7) * (nwg >> 3) + (wg >> 3);
    bx = s % nx;
    by = s / nx;
  } else {
    bx = blockIdx.x;
    by = blockIdx.y;
  }
}

// ---------------- split / transpose helpers ----------------

__global__ __launch_bounds__(256) void split_rows3(const float* __restrict__ in0,
                                                   const float* __restrict__ in1,
                                                   const float* __restrict__ in2,
                                                   u16* __restrict__ hi0, u16* __restrict__ lo0,
                                                   u16* __restrict__ hi1, u16* __restrict__ lo1,
                                                   u16* __restrict__ hi2, u16* __restrict__ lo2,
                                                   int n4) {
  int i = blockIdx.x * 256 + threadIdx.x;
  if (i >= n4) return;
  const float* in = blockIdx.z == 0 ? in0 : blockIdx.z == 1 ? in1 : in2;
  u16* hi = blockIdx.z == 0 ? hi0 : blockIdx.z == 1 ? hi1 : hi2;
  u16* lo = blockIdx.z == 0 ? lo0 : blockIdx.z == 1 ? lo1 : lo2;
  float4 t = ((const float4*)in)[i];
  ushort4 h, l;
  split2(t.x, h.x, l.x);
  split2(t.y, h.y, l.y);
  split2(t.z, h.z, l.z);
  split2(t.w, h.w, l.w);
  ((ushort4*)hi)[i] = h;
  ((ushort4*)lo)[i] = l;
}

__global__ __launch_bounds__(256) void split_transpose3(const float* __restrict__ in0,
                                                        const float* __restrict__ in1,
                                                        const float* __restrict__ in2,
                                                        u16* __restrict__ thi0, u16* __restrict__ tlo0,
                                                        u16* __restrict__ thi1, u16* __restrict__ tlo1,
                                                        u16* __restrict__ thi2, u16* __restrict__ tlo2,
                                                        int R, int C) {
  const float* in = blockIdx.z == 0 ? in0 : blockIdx.z == 1 ? in1 : in2;
  u16* thi = blockIdx.z == 0 ? thi0 : blockIdx.z == 1 ? thi1 : thi2;
  u16* tlo = blockIdx.z == 0 ? tlo0 : blockIdx.z == 1 ? tlo1 : tlo2;
  __shared__ float tile[32][33];
  int tx = threadIdx.x & 31, ty = threadIdx.x >> 5;
  int r0 = blockIdx.y * 32, c0 = blockIdx.x * 32;
#pragma unroll
  for (int j = 0; j < 32; j += 8)
    tile[ty + j][tx] = in[(size_t)(r0 + ty + j) * C + c0 + tx];
  __syncthreads();
#pragma unroll
  for (int j = 0; j < 32; j += 8) {
    float x = tile[tx][ty + j];
    u16 h, l;
    split2(x, h, l);
    size_t o = (size_t)(c0 + ty + j) * R + r0 + tx;
    thi[o] = h;
    tlo[o] = l;
  }
}

__global__ __launch_bounds__(256) void transpose_u16_2(const u16* __restrict__ in0,
                                                       const u16* __restrict__ in1,
                                                       u16* __restrict__ out0,
                                                       u16* __restrict__ out1, int R, int C) {
  const u16* in = blockIdx.z == 0 ? in0 : in1;
  u16* out = blockIdx.z == 0 ? out0 : out1;
  __shared__ u16 tile[32][33];
  int tx = threadIdx.x & 31, ty = threadIdx.x >> 5;
  int r0 = blockIdx.y * 32, c0 = blockIdx.x * 32;
#pragma unroll
  for (int j = 0; j < 32; j += 8)
    tile[ty + j][tx] = in[(size_t)(r0 + ty + j) * C + c0 + tx];
  __syncthreads();
#pragma unroll
  for (int j = 0; j < 32; j += 8)
    out[(size_t)(c0 + ty + j) * R + r0 + tx] = tile[tx][ty + j];
}

__global__ __launch_bounds__(256) void add_inplace(float* __restrict__ a,
                                                   const float* __restrict__ b, int n4) {
  int i = blockIdx.x * 256 + threadIdx.x;
  if (i >= n4) return;
  float4 x = ((const float4*)a)[i];
  float4 y = ((const float4*)b)[i];
  x.x += y.x; x.y += y.y; x.z += y.z; x.w += y.w;
  ((float4*)a)[i] = x;
}

// ---------------- deep-pipelined x3 GEMM (T2+T3+T4+T5, counted vmcnt) ----------------
// Tile 256 x 128, BK=32, 512 threads = 8 waves (2M x 4N), TRIPLE-buffered LDS (144KB).
// LDS row layout: [row][64]u16 = hi[0:32] | lo[0:32] (128B rows), 16B chunks
// XOR-swizzled: chunk_phys = chunk_logical ^ (row & 7) (bank-conflict-free, verified r9).
// Staging: linear LDS dest (global_load_lds), inverse-swizzled GLOBAL source.
// Pipeline: tile t issues t+2's loads (depth 2); p3 waits vmcnt(6) (t+1 landed,
// t+2 in flight) -- never drain-0 in the main loop [T4, m218].
template <int OUT_SPLIT>
__device__ __forceinline__ void gemm3b_body(
    const u16* __restrict__ Ahi, const u16* __restrict__ Alo, int lda,
    const u16* __restrict__ Bhi, const u16* __restrict__ Blo, int ldb,
    float* __restrict__ Cf, u16* __restrict__ Chi, u16* __restrict__ Clo, int ldc,
    int NT, int k0, float scale, int arow0, int bcol0) {
  constexpr int NCA = 256 * 8;             // A 16B-chunks per K-tile
  constexpr int NCB = 128 * 8;             // B 16B-chunks per K-tile
  constexpr int TISS = (NCA + NCB) / 512;  // 6 stage issues / thread / K-tile
  constexpr int H1 = TISS / 2;
  constexpr int BB = NCA * 8;              // B base (u16 index)
  constexpr int BUFSZ = (NCA + NCB) * 8;   // 24576 u16 = 48KB

  __shared__ alignas(16) u16 lds[3][BUFSZ];

  const int tid = threadIdx.x;
  const int lane = tid & 63;
  const int wid = tid >> 6;   // 0..7
  const int wr = wid >> 2;    // 0..1
  const int wc = wid & 3;     // 0..3
  const int frow = lane & 15;
  const int koct = lane >> 4; // 0..3

  // per-thread stage sources (inverse-swizzled global addresses)
  const u16* src[TISS];
  int loff[TISS];
#pragma unroll
  for (int j = 0; j < TISS; ++j) {
    int g = j * 512 + wid * 64 + lane;
    loff[j] = g * 8;
    if (g < NCA) {
      int r = g >> 3, ch = g & 7, c2 = ch ^ (r & 7);
      const u16* base = (c2 < 4) ? Ahi : Alo;
      src[j] = base + (size_t)(arow0 + r) * lda + k0 + (c2 & 3) * 8;
    } else {
      int gb = g - NCA;
      int r = gb >> 3, ch = gb & 7, c2 = ch ^ (r & 7);
      const u16* base = (c2 < 4) ? Bhi : Blo;
      src[j] = base + (size_t)(bcol0 + r) * ldb + k0 + (c2 & 3) * 8;
    }
  }

  f32x4 acc[8][2];
#pragma unroll
  for (int m = 0; m < 8; ++m)
#pragma unroll
    for (int n = 0; n < 2; ++n) acc[m][n] = (f32x4)0.0f;

  // prologue: stage tiles 0 and 1 (12 loads in flight), wait for tile 0 only
#pragma unroll
  for (int j = 0; j < TISS; ++j) stage16(src[j], &lds[0][loff[j]]);
#pragma unroll
  for (int j = 0; j < TISS; ++j) src[j] += BK;
  if (NT > 1) {
#pragma unroll
    for (int j = 0; j < TISS; ++j) stage16(src[j], &lds[1][loff[j]]);
#pragma unroll
    for (int j = 0; j < TISS; ++j) src[j] += BK;
    asm volatile("s_waitcnt vmcnt(6)" ::: "memory");
  } else {
    asm volatile("s_waitcnt vmcnt(0)" ::: "memory");
  }
  __builtin_amdgcn_sched_barrier(0);
  __builtin_amdgcn_s_barrier();

  for (int t = 0; t < NT; ++t) {
    const u16* cur = lds[t % 3];
    const u16* nx2 = lds[(t + 2) % 3];
    const bool st = (t + 2 < NT);
    s16x8 bh[2], bl[2];
#pragma unroll
    for (int p = 0; p < 4; ++p) {
      s16x8 ah[2], al[2];
      if (p == 0) {
#pragma unroll
        for (int n = 0; n < 2; ++n) {
          int br = wc * 32 + n * 16 + frow;
          bh[n] = *(const s16x8*)&cur[BB + br * 64 + ((koct ^ (br & 7)) << 3)];
          bl[n] = *(const s16x8*)&cur[BB + br * 64 + (((4 | koct) ^ (br & 7)) << 3)];
        }
      }
#pragma unroll
      for (int m = 0; m < 2; ++m) {
        int ar = wr * 128 + p * 32 + m * 16 + frow;
        ah[m] = *(const s16x8*)&cur[ar * 64 + ((koct ^ (ar & 7)) << 3)];
        al[m] = *(const s16x8*)&cur[ar * 64 + (((4 | koct) ^ (ar & 7)) << 3)];
      }
      if (st && p == 0) {
#pragma unroll
        for (int j = 0; j < H1; ++j) stage16(src[j], &nx2[loff[j]]);
      }
      if (st && p == 1) {
#pragma unroll
        for (int j = H1; j < TISS; ++j) stage16(src[j], &nx2[loff[j]]);
#pragma unroll
        for (int j = 0; j < TISS; ++j) src[j] += BK;
      }
      __builtin_amdgcn_sched_barrier(0);
      __builtin_amdgcn_s_barrier();
      asm volatile("s_waitcnt lgkmcnt(0)" ::: "memory");
      __builtin_amdgcn_sched_barrier(0);
      __builtin_amdgcn_s_setprio(1);
#pragma unroll
      for (int m = 0; m < 2; ++m)
#pragma unroll
        for (int n = 0; n < 2; ++n) {
          acc[p * 2 + m][n] =
              __builtin_amdgcn_mfma_f32_16x16x32_bf16(ah[m], bh[n], acc[p * 2 + m][n], 0, 0, 0);
          acc[p * 2 + m][n] =
              __builtin_amdgcn_mfma_f32_16x16x32_bf16(ah[m], bl[n], acc[p * 2 + m][n], 0, 0, 0);
          acc[p * 2 + m][n] =
              __builtin_amdgcn_mfma_f32_16x16x32_bf16(al[m], bh[n], acc[p * 2 + m][n], 0, 0, 0);
        }
      __builtin_amdgcn_s_setprio(0);
      __builtin_amdgcn_sched_barrier(0);
      if (p == 3) {
        // counted wait: allow t+2's TISS loads to stay in flight; t+1's are done.
        if (st) {
          asm volatile("s_waitcnt vmcnt(6)" ::: "memory");
        } else {
          asm volatile("s_waitcnt vmcnt(0)" ::: "memory");
        }
        __builtin_amdgcn_sched_barrier(0);
      }
      __builtin_amdgcn_s_barrier();
    }
  }

  // epilogue: C/D layout col=lane&15, row=(lane>>4)*4+reg [m89/m91]
  const int rb = arow0 + wr * 128 + koct * 4;
  const int cb = bcol0 + wc * 32 + frow;
#pragma unroll
  for (int mg = 0; mg < 8; ++mg)
#pragma unroll
    for (int n = 0; n < 2; ++n)
#pragma unroll
      for (int r = 0; r < 4; ++r) {
        int row = rb + mg * 16 + r;
        int col = cb + n * 16;
        float val = acc[mg][n][r] * scale;
        if (OUT_SPLIT) {
          u16 h, l;
          split2(val, h, l);
          Chi[(size_t)row * ldc + col] = h;
          Clo[(size_t)row * ldc + col] = l;
        } else {
          Cf[(size_t)row * ldc + col] = val;
        }
      }
}

// scores: 256x128 tiles, fp32 out
__global__ __launch_bounds__(512, 2) void scores8p(
    const u16* __restrict__ Ahi, const u16* __restrict__ Alo, int lda,
    const u16* __restrict__ Bhi, const u16* __restrict__ Blo, int ldb,
    float* __restrict__ Cf, int ldc, int NT, float scale) {
  int bx, by;
  xcd_swz(bx, by);
  gemm3b_body<0>(Ahi, Alo, lda, Bhi, Blo, ldb, Cf, nullptr, nullptr, ldc,
                 NT, 0, scale, by * 256, bx * 128);
}

// fused projections: 256x128 tiles, split-bf16 out, z selects matrix
__global__ __launch_bounds__(512, 2) void proj8p(
    const u16* __restrict__ a0h, const u16* __restrict__ a0l,
    const u16* __restrict__ a1h, const u16* __restrict__ a1l,
    const u16* __restrict__ a2h, const u16* __restrict__ a2l,
    const u16* __restrict__ b0h, const u16* __restrict__ b0l,
    const u16* __restrict__ b1h, const u16* __restrict__ b1l,
    const u16* __restrict__ b2h, const u16* __restrict__ b2l,
    u16* __restrict__ c0h, u16* __restrict__ c0l,
    u16* __restrict__ c1h, u16* __restrict__ c1l,
    u16* __restrict__ c2h, u16* __restrict__ c2l,
    int D, float scale0) {
  const int z = blockIdx.z;
  const u16* Ah = z == 0 ? a0h : z == 1 ? a1h : a2h;
  const u16* Al = z == 0 ? a0l : z == 1 ? a1l : a2l;
  const u16* Bh = z == 0 ? b0h : z == 1 ? b1h : b2h;
  const u16* Bl = z == 0 ? b0l : z == 1 ? b1l : b2l;
  u16* Ch = z == 0 ? c0h : z == 1 ? c1h : c2h;
  u16* Cl = z == 0 ? c0l : z == 1 ? c1l : c2l;
  float scale = z == 0 ? scale0 : 1.0f;
  int bx, by;
  xcd_swz(bx, by);
  gemm3b_body<1>(Ah, Al, D, Bh, Bl, D, nullptr, Ch, Cl, D,
                 D / BK, 0, scale, by * 256, bx * 128);
}

// PV: 256x128 tiles, split-K=2 (z=0 -> Cf0 over K[0,2048), z=1 -> Cf1 over K[2048,4096))
__global__ __launch_bounds__(512, 2) void pv8p(
    const u16* __restrict__ Ahi, const u16* __restrict__ Alo, int lda,
    const u16* __restrict__ Bhi, const u16* __restrict__ Blo, int ldb,
    float* __restrict__ Cf0, float* __restrict__ Cf1, int ldc, int KH) {
  float* Cf = blockIdx.z == 0 ? Cf0 : Cf1;
  int bx, by;
  xcd_swz(bx, by);
  gemm3b_body<0>(Ahi, Alo, lda, Bhi, Blo, ldb, Cf, nullptr, nullptr, ldc,
                 KH / BK, blockIdx.z * KH, 1.0f, by * 256, bx * 128);
}

// ---------------- row softmax, in-place fp32 -> packed hi/lo bf16 ----------------
__global__ __launch_bounds__(256) void softmax_rows(float* __restrict__ S, int N) {
  const int tid = threadIdx.x;
  float* row = S + (size_t)blockIdx.x * N;
  const float4* row4 = (const float4*)row;
  float v[16];
#pragma unroll
  for (int i = 0; i < 4; ++i) {
    float4 t = row4[tid + i * 256];
    v[i * 4 + 0] = t.x;
    v[i * 4 + 1] = t.y;
    v[i * 4 + 2] = t.z;
    v[i * 4 + 3] = t.w;
  }
  float m = -__builtin_inff();
#pragma unroll
  for (int i = 0; i < 16; ++i) m = fmaxf(m, v[i]);
#pragma unroll
  for (int o = 32; o > 0; o >>= 1) m = fmaxf(m, __shfl_xor(m, o));
  __shared__ float redm[4];
  __shared__ float reds[4];
  const int wid = tid >> 6;
  if ((tid & 63) == 0) redm[wid] = m;
  __syncthreads();   // orders all row reads above before in-place writes below
  m = fmaxf(fmaxf(redm[0], redm[1]), fmaxf(redm[2], redm[3]));

  float s = 0.f;
#pragma unroll
  for (int i = 0; i < 16; ++i) {
    v[i] = __expf(v[i] - m);
    s += v[i];
  }
#pragma unroll
  for (int o = 32; o > 0; o >>= 1) s += __shfl_xor(s, o);
  if ((tid & 63) == 0) reds[wid] = s;
  __syncthreads();
  s = reds[0] + reds[1] + reds[2] + reds[3];
  float inv = 1.0f / s;

  u16* hrow = (u16*)row;
  u16* lrow = hrow + N;
#pragma unroll
  for (int i = 0; i < 4; ++i) {
    ushort4 h4, l4;
    split2(v[i * 4 + 0] * inv, h4.x, l4.x);
    split2(v[i * 4 + 1] * inv, h4.y, l4.y);
    split2(v[i * 4 + 2] * inv, h4.z, l4.z);
    split2(v[i * 4 + 3] * inv, h4.w, l4.w);
    ((ushort4*)hrow)[tid + i * 256] = h4;
    ((ushort4*)lrow)[tid + i * 256] = l4;
  }
}

// ---------------- launcher ----------------
extern "C" void kernel_launch(void* const* d_in, const int* in_sizes, int n_in,
                              void* d_out, int out_size, void* d_ws, size_t ws_size,
                              hipStream_t stream) {
  (void)in_sizes; (void)n_in; (void)out_size; (void)ws_size;
  const float* q  = (const float*)d_in[0];
  const float* k  = (const float*)d_in[1];
  const float* v  = (const float*)d_in[2];
  const float* Wq = (const float*)d_in[3];
  const float* Wk = (const float*)d_in[4];
  const float* Wv = (const float*)d_in[5];
  float* out = (float*)d_out;

  char* ws = (char*)d_ws;
  const size_t MB = 1ull << 20;
  u16* q_hi = (u16*)(ws + 0 * MB);
  u16* q_lo = (u16*)(ws + 8 * MB);
  u16* k_hi = (u16*)(ws + 16 * MB);
  u16* k_lo = (u16*)(ws + 24 * MB);
  u16* v_hi = (u16*)(ws + 32 * MB);
  u16* v_lo = (u16*)(ws + 40 * MB);
  u16* V_hi = (u16*)(ws + 48 * MB);
  u16* V_lo = (u16*)(ws + 56 * MB);
  float* S  = (float*)(ws + 0 * MB);  // 64 MB, live phase 5+
  u16* WqT_hi = (u16*)(ws + 64 * MB);
  u16* WqT_lo = (u16*)(ws + 66 * MB);
  u16* WkT_hi = (u16*)(ws + 68 * MB);
  u16* WkT_lo = (u16*)(ws + 70 * MB);
  u16* WvT_hi = (u16*)(ws + 72 * MB);
  u16* WvT_lo = (u16*)(ws + 74 * MB);
  u16* Q_hi = (u16*)(ws + 76 * MB);
  u16* Q_lo = (u16*)(ws + 84 * MB);
  u16* K_hi = (u16*)(ws + 92 * MB);
  u16* K_lo = (u16*)(ws + 100 * MB);
  u16* VT_hi = (u16*)(ws + 108 * MB);
  u16* VT_lo = (u16*)(ws + 116 * MB);
  float* PVp1 = (float*)(ws + 76 * MB);  // 16 MB; aliases dead Q splits during PV
  // high-water: 124 MB

  const int NQ = 4096, NKV = 4096, D = 1024;

  // 1. split q,k,v
  int n4 = NQ * D / 4;
  split_rows3<<<dim3(n4 / 256, 1, 3), 256, 0, stream>>>(q, k, v, q_hi, q_lo, k_hi, k_lo,
                                                        v_hi, v_lo, n4);

  // 2. split-transpose weights
  split_transpose3<<<dim3(D / 32, D / 32, 3), 256, 0, stream>>>(
      Wq, Wk, Wv, WqT_hi, WqT_lo, WkT_hi, WkT_lo, WvT_hi, WvT_lo, D, D);

  // 3. fused projections (256x128, 384 blocks); Q pre-scaled by 1/32
  proj8p<<<dim3(D / 128, NQ / 256, 3), 512, 0, stream>>>(
      q_hi, q_lo, k_hi, k_lo, v_hi, v_lo,
      WqT_hi, WqT_lo, WkT_hi, WkT_lo, WvT_hi, WvT_lo,
      Q_hi, Q_lo, K_hi, K_lo, V_hi, V_lo, D, 0.03125f);

  // 4. transpose V -> V^T (must precede phase 5: S overwrites V's storage)
  transpose_u16_2<<<dim3(D / 32, NKV / 32, 2), 256, 0, stream>>>(V_hi, V_lo, VT_hi, VT_lo,
                                                                 NKV, D);

  // 5. scores S = (Q/32) @ K^T (256x128, 512 blocks = 2 exact rounds)
  scores8p<<<dim3(NKV / 128, NQ / 256), 512, 0, stream>>>(Q_hi, Q_lo, D, K_hi, K_lo, D,
                                                          S, NKV, D / BK, 1.0f);

  // 6. row softmax in-place: fp32 row -> packed P_hi | P_lo bf16 halves
  softmax_rows<<<NQ, 256, 0, stream>>>(S, NKV);

  // 7. out = P @ V (256x128, split-K=2 -> 256 blocks = 1 round)
  pv8p<<<dim3(D / 128, NQ / 256, 2), 512, 0, stream>>>(
      (u16*)S, (u16*)S + NKV, 2 * NKV, VT_hi, VT_lo, NKV, out, PVp1, D, NKV / 2);

  // 8. out += partial
  add_inplace<<<NQ * D / 4 / 256, 256, 0, stream>>>(out, PVp1, NQ * D / 4);
}

// Round 14
// 399.021 us; speedup vs baseline: 1.0819x; 1.0819x over previous
//
#include <hip/hip_runtime.h>
#include <hip/hip_bf16.h>
#include <stdint.h>

typedef float  f32x4  __attribute__((ext_vector_type(4)));
typedef short  s16x8  __attribute__((ext_vector_type(8)));
typedef unsigned short u16;

#define BK 32

__device__ inline u16 f32_to_bf16_rn(float f) {
  uint32_t u = __builtin_bit_cast(uint32_t, f);
  u += 0x7FFFu + ((u >> 16) & 1u);
  return (u16)(u >> 16);
}
__device__ inline float bf16u_to_f32(u16 h) {
  uint32_t u = ((uint32_t)h) << 16;
  return __builtin_bit_cast(float, u);
}
__device__ inline void split2(float x, u16& hi, u16& lo) {
  u16 h = f32_to_bf16_rn(x);
  lo = f32_to_bf16_rn(x - bf16u_to_f32(h));
  hi = h;
}

__device__ inline void stage16(const u16* g, const u16* l) {
  __builtin_amdgcn_global_load_lds((const __attribute__((address_space(1))) uint32_t*)g,
                                   (__attribute__((address_space(3))) uint32_t*)(u16*)l,
                                   16, 0, 0);
}

// XCD-aware block swizzle (m204 bijective; needs gridDim.x*gridDim.y % 8 == 0)
__device__ inline void xcd_swz(int& bx, int& by) {
  int nx = gridDim.x, nwg = nx * gridDim.y;
  if ((nwg & 7) == 0) {
    int wg = blockIdx.x + nx * blockIdx.y;
    int s = (wg & 7) * (nwg >> 3) + (wg >> 3);
    bx = s % nx;
    by = s / nx;
  } else {
    bx = blockIdx.x;
    by = blockIdx.y;
  }
}

// ---------------- split / transpose helpers ----------------

__global__ __launch_bounds__(256) void split_rows3(const float* __restrict__ in0,
                                                   const float* __restrict__ in1,
                                                   const float* __restrict__ in2,
                                                   u16* __restrict__ hi0, u16* __restrict__ lo0,
                                                   u16* __restrict__ hi1, u16* __restrict__ lo1,
                                                   u16* __restrict__ hi2, u16* __restrict__ lo2,
                                                   int n4) {
  int i = blockIdx.x * 256 + threadIdx.x;
  if (i >= n4) return;
  const float* in = blockIdx.z == 0 ? in0 : blockIdx.z == 1 ? in1 : in2;
  u16* hi = blockIdx.z == 0 ? hi0 : blockIdx.z == 1 ? hi1 : hi2;
  u16* lo = blockIdx.z == 0 ? lo0 : blockIdx.z == 1 ? lo1 : lo2;
  float4 t = ((const float4*)in)[i];
  ushort4 h, l;
  split2(t.x, h.x, l.x);
  split2(t.y, h.y, l.y);
  split2(t.z, h.z, l.z);
  split2(t.w, h.w, l.w);
  ((ushort4*)hi)[i] = h;
  ((ushort4*)lo)[i] = l;
}

__global__ __launch_bounds__(256) void split_transpose3(const float* __restrict__ in0,
                                                        const float* __restrict__ in1,
                                                        const float* __restrict__ in2,
                                                        u16* __restrict__ thi0, u16* __restrict__ tlo0,
                                                        u16* __restrict__ thi1, u16* __restrict__ tlo1,
                                                        u16* __restrict__ thi2, u16* __restrict__ tlo2,
                                                        int R, int C) {
  const float* in = blockIdx.z == 0 ? in0 : blockIdx.z == 1 ? in1 : in2;
  u16* thi = blockIdx.z == 0 ? thi0 : blockIdx.z == 1 ? thi1 : thi2;
  u16* tlo = blockIdx.z == 0 ? tlo0 : blockIdx.z == 1 ? tlo1 : tlo2;
  __shared__ float tile[32][33];
  int tx = threadIdx.x & 31, ty = threadIdx.x >> 5;
  int r0 = blockIdx.y * 32, c0 = blockIdx.x * 32;
#pragma unroll
  for (int j = 0; j < 32; j += 8)
    tile[ty + j][tx] = in[(size_t)(r0 + ty + j) * C + c0 + tx];
  __syncthreads();
#pragma unroll
  for (int j = 0; j < 32; j += 8) {
    float x = tile[tx][ty + j];
    u16 h, l;
    split2(x, h, l);
    size_t o = (size_t)(c0 + ty + j) * R + r0 + tx;
    thi[o] = h;
    tlo[o] = l;
  }
}

__global__ __launch_bounds__(256) void transpose_u16_2(const u16* __restrict__ in0,
                                                       const u16* __restrict__ in1,
                                                       u16* __restrict__ out0,
                                                       u16* __restrict__ out1, int R, int C) {
  const u16* in = blockIdx.z == 0 ? in0 : in1;
  u16* out = blockIdx.z == 0 ? out0 : out1;
  __shared__ u16 tile[32][33];
  int tx = threadIdx.x & 31, ty = threadIdx.x >> 5;
  int r0 = blockIdx.y * 32, c0 = blockIdx.x * 32;
#pragma unroll
  for (int j = 0; j < 32; j += 8)
    tile[ty + j][tx] = in[(size_t)(r0 + ty + j) * C + c0 + tx];
  __syncthreads();
#pragma unroll
  for (int j = 0; j < 32; j += 8)
    out[(size_t)(c0 + ty + j) * R + r0 + tx] = tile[tx][ty + j];
}

__global__ __launch_bounds__(256) void add_inplace(float* __restrict__ a,
                                                   const float* __restrict__ b, int n4) {
  int i = blockIdx.x * 256 + threadIdx.x;
  if (i >= n4) return;
  float4 x = ((const float4*)a)[i];
  float4 y = ((const float4*)b)[i];
  x.x += y.x; x.y += y.y; x.z += y.z; x.w += y.w;
  ((float4*)a)[i] = x;
}

// ------- counted-vmcnt x3 GEMM, 256xTBN tile, 2 LDS buffers (T2+T3+T4+T5) -------
// 512 threads = 8 waves (2M x 4N). Per K-tile: A = 2048 16B-chunks, B = TBN*8.
// Issue ORDER per tile: G1 = {B all, A rows[0,64), A rows[128,192)} (TISS-2 issues),
//                       G2 = {A rows[64,128), A rows[192,256)}      (2 issues).
// Phases p read A rows {p*32..p*32+31} U {128+p*32..}: p0/p1 covered by G1, p2/p3 by G2.
// Pipeline: during tile t: p0 issues G1(t+1), p1 issues G2(t+1) (into buffer freed at
// end of tile t-1). Waits: after p1 MFMA: vmcnt(TISS) retires G2(t); after p3 MFMA:
// vmcnt(2) retires G1(t+1). Never drain-0 mid-loop [T4, m218]. Ledger verified incl.
// NT=1 and tail (t=NT-1: p1 wait -> vmcnt(0), p3 wait skipped).
// XOR swizzle: chunk_phys = chunk_logical ^ (row&7); inverse-swizzled global source,
// linear LDS dest (rule #21). Bank-conflict 0 verified r9/r13.
template <int TBN, int OUT_SPLIT>
__device__ __forceinline__ void gemm2c_body(
    const u16* __restrict__ Ahi, const u16* __restrict__ Alo, int lda,
    const u16* __restrict__ Bhi, const u16* __restrict__ Blo, int ldb,
    float* __restrict__ Cf, u16* __restrict__ Chi, u16* __restrict__ Clo, int ldc,
    int NT, int k0, float scale, int arow0, int bcol0) {
  constexpr int NCA = 2048;                // A 16B-chunks per K-tile (256 rows x 8)
  constexpr int NCB = TBN * 8;
  constexpr int NBI = NCB / 512;           // B issues per thread
  constexpr int TISS = NBI + 4;            // total issues per thread per K-tile
  constexpr int FN = TBN / 64;             // B frags per wave
  constexpr int BB = NCA * 8;              // B base (u16 index)

  __shared__ alignas(16) u16 lds[2][(NCA + NCB) * 8];

  const int tid = threadIdx.x;
  const int lane = tid & 63;
  const int wid = tid >> 6;   // 0..7
  const int wr = wid >> 2;    // 0..1
  const int wc = wid & 3;     // 0..3
  const int frow = lane & 15;
  const int koct = lane >> 4; // 0..3

  // per-thread stage sources in ISSUE ORDER: B(NBI), A j0, A j2 | A j1, A j3
  const u16* src[TISS];
  int loff[TISS];
  const int aj[4] = {0, 2, 1, 3};
#pragma unroll
  for (int s = 0; s < TISS; ++s) {
    if (s < NBI) {
      int g = s * 512 + tid;               // B chunk
      int r = g >> 3, ch = g & 7, c2 = ch ^ (r & 7);
      const u16* base = (c2 < 4) ? Bhi : Blo;
      src[s] = base + (size_t)(bcol0 + r) * ldb + k0 + (c2 & 3) * 8;
      loff[s] = BB + g * 8;
    } else {
      int g = aj[s - NBI] * 512 + tid;     // A chunk
      int r = g >> 3, ch = g & 7, c2 = ch ^ (r & 7);
      const u16* base = (c2 < 4) ? Ahi : Alo;
      src[s] = base + (size_t)(arow0 + r) * lda + k0 + (c2 & 3) * 8;
      loff[s] = g * 8;
    }
  }

  f32x4 acc[8][FN];
#pragma unroll
  for (int m = 0; m < 8; ++m)
#pragma unroll
    for (int n = 0; n < FN; ++n) acc[m][n] = (f32x4)0.0f;

  // prologue: stage tile 0 (TISS loads); G1 landed, G2 may fly
#pragma unroll
  for (int s = 0; s < TISS; ++s) stage16(src[s], &lds[0][loff[s]]);
#pragma unroll
  for (int s = 0; s < TISS; ++s) src[s] += BK;
  asm volatile("s_waitcnt vmcnt(2)" ::: "memory");
  __builtin_amdgcn_sched_barrier(0);
  __builtin_amdgcn_s_barrier();

  for (int t = 0; t < NT; ++t) {
    const u16* cur = lds[t & 1];
    const u16* nxt = lds[(t + 1) & 1];
    const bool st = (t + 1 < NT);
    s16x8 bh[FN], bl[FN];
#pragma unroll
    for (int p = 0; p < 4; ++p) {
      s16x8 ah[2], al[2];
      if (p == 0) {
#pragma unroll
        for (int n = 0; n < FN; ++n) {
          int br = wc * (TBN / 4) + n * 16 + frow;
          bh[n] = *(const s16x8*)&cur[BB + br * 64 + ((koct ^ (br & 7)) << 3)];
          bl[n] = *(const s16x8*)&cur[BB + br * 64 + (((4 | koct) ^ (br & 7)) << 3)];
        }
      }
#pragma unroll
      for (int m = 0; m < 2; ++m) {
        int ar = wr * 128 + p * 32 + m * 16 + frow;
        ah[m] = *(const s16x8*)&cur[ar * 64 + ((koct ^ (ar & 7)) << 3)];
        al[m] = *(const s16x8*)&cur[ar * 64 + (((4 | koct) ^ (ar & 7)) << 3)];
      }
      if (st && p == 0) {
#pragma unroll
        for (int s = 0; s < TISS - 2; ++s) stage16(src[s], &nxt[loff[s]]);   // G1(t+1)
      }
      if (st && p == 1) {
#pragma unroll
        for (int s = TISS - 2; s < TISS; ++s) stage16(src[s], &nxt[loff[s]]); // G2(t+1)
#pragma unroll
        for (int s = 0; s < TISS; ++s) src[s] += BK;
      }
      __builtin_amdgcn_sched_barrier(0);
      __builtin_amdgcn_s_barrier();
      asm volatile("s_waitcnt lgkmcnt(0)" ::: "memory");
      __builtin_amdgcn_sched_barrier(0);
      __builtin_amdgcn_s_setprio(1);
#pragma unroll
      for (int m = 0; m < 2; ++m)
#pragma unroll
        for (int n = 0; n < FN; ++n) {
          acc[p * 2 + m][n] =
              __builtin_amdgcn_mfma_f32_16x16x32_bf16(ah[m], bh[n], acc[p * 2 + m][n], 0, 0, 0);
          acc[p * 2 + m][n] =
              __builtin_amdgcn_mfma_f32_16x16x32_bf16(ah[m], bl[n], acc[p * 2 + m][n], 0, 0, 0);
          acc[p * 2 + m][n] =
              __builtin_amdgcn_mfma_f32_16x16x32_bf16(al[m], bh[n], acc[p * 2 + m][n], 0, 0, 0);
        }
      __builtin_amdgcn_s_setprio(0);
      __builtin_amdgcn_sched_barrier(0);
      if (p == 1) {
        // retire G2(t) before p2 reads rows [64,128)|[192,256); t+1's TISS stay in flight
        if (st) {
          asm volatile("s_waitcnt vmcnt(%0)" ::"i"(TISS) : "memory");
        } else {
          asm volatile("s_waitcnt vmcnt(0)" ::: "memory");
        }
        __builtin_amdgcn_sched_barrier(0);
      }
      if (p == 3 && st) {
        // retire G1(t+1) before next tile's p0; G2(t+1) stays in flight
        asm volatile("s_waitcnt vmcnt(2)" ::: "memory");
        __builtin_amdgcn_sched_barrier(0);
      }
      __builtin_amdgcn_s_barrier();
    }
  }

  // epilogue: C/D layout col=lane&15, row=(lane>>4)*4+reg [m89/m91]
  const int rb = arow0 + wr * 128 + koct * 4;
  const int cb = bcol0 + wc * (TBN / 4) + frow;
#pragma unroll
  for (int mg = 0; mg < 8; ++mg)
#pragma unroll
    for (int n = 0; n < FN; ++n)
#pragma unroll
      for (int r = 0; r < 4; ++r) {
        int row = rb + mg * 16 + r;
        int col = cb + n * 16;
        float val = acc[mg][n][r] * scale;
        if (OUT_SPLIT) {
          u16 h, l;
          split2(val, h, l);
          Chi[(size_t)row * ldc + col] = h;
          Clo[(size_t)row * ldc + col] = l;
        } else {
          Cf[(size_t)row * ldc + col] = val;
        }
      }
}

// scores: 256x256 tiles, fp32 out, grid (16,16) = 1 exact round
__global__ __launch_bounds__(512, 2) void scores8p(
    const u16* __restrict__ Ahi, const u16* __restrict__ Alo, int lda,
    const u16* __restrict__ Bhi, const u16* __restrict__ Blo, int ldb,
    float* __restrict__ Cf, int ldc, int NT, float scale) {
  int bx, by;
  xcd_swz(bx, by);
  gemm2c_body<256, 0>(Ahi, Alo, lda, Bhi, Blo, ldb, Cf, nullptr, nullptr, ldc,
                      NT, 0, scale, by * 256, bx * 256);
}

// fused projections: 256x256 tiles, split-bf16 out, z selects matrix; grid (4,16,3)
__global__ __launch_bounds__(512, 2) void proj8p(
    const u16* __restrict__ a0h, const u16* __restrict__ a0l,
    const u16* __restrict__ a1h, const u16* __restrict__ a1l,
    const u16* __restrict__ a2h, const u16* __restrict__ a2l,
    const u16* __restrict__ b0h, const u16* __restrict__ b0l,
    const u16* __restrict__ b1h, const u16* __restrict__ b1l,
    const u16* __restrict__ b2h, const u16* __restrict__ b2l,
    u16* __restrict__ c0h, u16* __restrict__ c0l,
    u16* __restrict__ c1h, u16* __restrict__ c1l,
    u16* __restrict__ c2h, u16* __restrict__ c2l,
    int D, float scale0) {
  const int z = blockIdx.z;
  const u16* Ah = z == 0 ? a0h : z == 1 ? a1h : a2h;
  const u16* Al = z == 0 ? a0l : z == 1 ? a1l : a2l;
  const u16* Bh = z == 0 ? b0h : z == 1 ? b1h : b2h;
  const u16* Bl = z == 0 ? b0l : z == 1 ? b1l : b2l;
  u16* Ch = z == 0 ? c0h : z == 1 ? c1h : c2h;
  u16* Cl = z == 0 ? c0l : z == 1 ? c1l : c2l;
  float scale = z == 0 ? scale0 : 1.0f;
  int bx, by;
  xcd_swz(bx, by);
  gemm2c_body<256, 1>(Ah, Al, D, Bh, Bl, D, nullptr, Ch, Cl, D,
                      D / BK, 0, scale, by * 256, bx * 256);
}

// PV: 256x128 tiles, split-K=2; grid (8,16,2) = 1 exact round
__global__ __launch_bounds__(512, 2) void pv8p(
    const u16* __restrict__ Ahi, const u16* __restrict__ Alo, int lda,
    const u16* __restrict__ Bhi, const u16* __restrict__ Blo, int ldb,
    float* __restrict__ Cf0, float* __restrict__ Cf1, int ldc, int KH) {
  float* Cf = blockIdx.z == 0 ? Cf0 : Cf1;
  int bx, by;
  xcd_swz(bx, by);
  gemm2c_body<128, 0>(Ahi, Alo, lda, Bhi, Blo, ldb, Cf, nullptr, nullptr, ldc,
                      KH / BK, blockIdx.z * KH, 1.0f, by * 256, bx * 128);
}

// ---------------- row softmax, in-place fp32 -> packed hi/lo bf16 ----------------
__global__ __launch_bounds__(256) void softmax_rows(float* __restrict__ S, int N) {
  const int tid = threadIdx.x;
  float* row = S + (size_t)blockIdx.x * N;
  const float4* row4 = (const float4*)row;
  float v[16];
#pragma unroll
  for (int i = 0; i < 4; ++i) {
    float4 t = row4[tid + i * 256];
    v[i * 4 + 0] = t.x;
    v[i * 4 + 1] = t.y;
    v[i * 4 + 2] = t.z;
    v[i * 4 + 3] = t.w;
  }
  float m = -__builtin_inff();
#pragma unroll
  for (int i = 0; i < 16; ++i) m = fmaxf(m, v[i]);
#pragma unroll
  for (int o = 32; o > 0; o >>= 1) m = fmaxf(m, __shfl_xor(m, o));
  __shared__ float redm[4];
  __shared__ float reds[4];
  const int wid = tid >> 6;
  if ((tid & 63) == 0) redm[wid] = m;
  __syncthreads();   // orders all row reads above before in-place writes below
  m = fmaxf(fmaxf(redm[0], redm[1]), fmaxf(redm[2], redm[3]));

  float s = 0.f;
#pragma unroll
  for (int i = 0; i < 16; ++i) {
    v[i] = __expf(v[i] - m);
    s += v[i];
  }
#pragma unroll
  for (int o = 32; o > 0; o >>= 1) s += __shfl_xor(s, o);
  if ((tid & 63) == 0) reds[wid] = s;
  __syncthreads();
  s = reds[0] + reds[1] + reds[2] + reds[3];
  float inv = 1.0f / s;

  u16* hrow = (u16*)row;
  u16* lrow = hrow + N;
#pragma unroll
  for (int i = 0; i < 4; ++i) {
    ushort4 h4, l4;
    split2(v[i * 4 + 0] * inv, h4.x, l4.x);
    split2(v[i * 4 + 1] * inv, h4.y, l4.y);
    split2(v[i * 4 + 2] * inv, h4.z, l4.z);
    split2(v[i * 4 + 3] * inv, h4.w, l4.w);
    ((ushort4*)hrow)[tid + i * 256] = h4;
    ((ushort4*)lrow)[tid + i * 256] = l4;
  }
}

// ---------------- launcher ----------------
extern "C" void kernel_launch(void* const* d_in, const int* in_sizes, int n_in,
                              void* d_out, int out_size, void* d_ws, size_t ws_size,
                              hipStream_t stream) {
  (void)in_sizes; (void)n_in; (void)out_size; (void)ws_size;
  const float* q  = (const float*)d_in[0];
  const float* k  = (const float*)d_in[1];
  const float* v  = (const float*)d_in[2];
  const float* Wq = (const float*)d_in[3];
  const float* Wk = (const float*)d_in[4];
  const float* Wv = (const float*)d_in[5];
  float* out = (float*)d_out;

  char* ws = (char*)d_ws;
  const size_t MB = 1ull << 20;
  u16* q_hi = (u16*)(ws + 0 * MB);
  u16* q_lo = (u16*)(ws + 8 * MB);
  u16* k_hi = (u16*)(ws + 16 * MB);
  u16* k_lo = (u16*)(ws + 24 * MB);
  u16* v_hi = (u16*)(ws + 32 * MB);
  u16* v_lo = (u16*)(ws + 40 * MB);
  u16* V_hi = (u16*)(ws + 48 * MB);
  u16* V_lo = (u16*)(ws + 56 * MB);
  float* S  = (float*)(ws + 0 * MB);  // 64 MB, live phase 5+
  u16* WqT_hi = (u16*)(ws + 64 * MB);
  u16* WqT_lo = (u16*)(ws + 66 * MB);
  u16* WkT_hi = (u16*)(ws + 68 * MB);
  u16* WkT_lo = (u16*)(ws + 70 * MB);
  u16* WvT_hi = (u16*)(ws + 72 * MB);
  u16* WvT_lo = (u16*)(ws + 74 * MB);
  u16* Q_hi = (u16*)(ws + 76 * MB);
  u16* Q_lo = (u16*)(ws + 84 * MB);
  u16* K_hi = (u16*)(ws + 92 * MB);
  u16* K_lo = (u16*)(ws + 100 * MB);
  u16* VT_hi = (u16*)(ws + 108 * MB);
  u16* VT_lo = (u16*)(ws + 116 * MB);
  float* PVp1 = (float*)(ws + 76 * MB);  // 16 MB; aliases dead Q splits during PV
  // high-water: 124 MB

  const int NQ = 4096, NKV = 4096, D = 1024;

  // 1. split q,k,v
  int n4 = NQ * D / 4;
  split_rows3<<<dim3(n4 / 256, 1, 3), 256, 0, stream>>>(q, k, v, q_hi, q_lo, k_hi, k_lo,
                                                        v_hi, v_lo, n4);

  // 2. split-transpose weights
  split_transpose3<<<dim3(D / 32, D / 32, 3), 256, 0, stream>>>(
      Wq, Wk, Wv, WqT_hi, WqT_lo, WkT_hi, WkT_lo, WvT_hi, WvT_lo, D, D);

  // 3. fused projections (256x256, 192 blocks = 1 round); Q pre-scaled by 1/32
  proj8p<<<dim3(D / 256, NQ / 256, 3), 512, 0, stream>>>(
      q_hi, q_lo, k_hi, k_lo, v_hi, v_lo,
      WqT_hi, WqT_lo, WkT_hi, WkT_lo, WvT_hi, WvT_lo,
      Q_hi, Q_lo, K_hi, K_lo, V_hi, V_lo, D, 0.03125f);

  // 4. transpose V -> V^T (must precede phase 5: S overwrites V's storage)
  transpose_u16_2<<<dim3(D / 32, NKV / 32, 2), 256, 0, stream>>>(V_hi, V_lo, VT_hi, VT_lo,
                                                                 NKV, D);

  // 5. scores S = (Q/32) @ K^T (256x256, 256 blocks = 1 exact round)
  scores8p<<<dim3(NKV / 256, NQ / 256), 512, 0, stream>>>(Q_hi, Q_lo, D, K_hi, K_lo, D,
                                                          S, NKV, D / BK, 1.0f);

  // 6. row softmax in-place: fp32 row -> packed P_hi | P_lo bf16 halves
  softmax_rows<<<NQ, 256, 0, stream>>>(S, NKV);

  // 7. out = P @ V (256x128, split-K=2 -> 256 blocks = 1 round)
  pv8p<<<dim3(D / 128, NQ / 256, 2), 512, 0, stream>>>(
      (u16*)S, (u16*)S + NKV, 2 * NKV, VT_hi, VT_lo, NKV, out, PVp1, D, NKV / 2);

  // 8. out += partial
  add_inplace<<<NQ * D / 4 / 256, 256, 0, stream>>>(out, PVp1, NQ * D / 4);
}